// Round 4
// baseline (779.514 us; speedup 1.0000x reference)
//
#include <hip/hip_runtime.h>
#include <cstddef>

#define NSP   56
#define NPX   3136
#define CINN  32
#define COUTN 64
#define NB    128
#define CO_PB 8
#define NSTRIP 14            // 14 strips x 4 rows
#define THR   256            // 4 waves; ty=tid>>6 (0..3), tx=tid&63 (active<56)
#define XP    33             // padded channel stride (bank-conflict-free: 33%32=1)

// ---- pass 1: conv(+bias,relu) in XLA:CPU/Eigen rounding order, y + argmax ----
__global__ __launch_bounds__(THR, 3)
void conv_emul_pass1(const float* __restrict__ x,
                     const float* __restrict__ Wt,
                     const float* __restrict__ bias,
                     float* __restrict__ y,      // d_out: relu(conv+bias)
                     int* __restrict__ amax)     // d_ws: [NB*COUTN] argmax idx
{
    __shared__ float xs[6][58][XP];
    __shared__ float rv[4][CO_PB];
    __shared__ int   ri[4][CO_PB];

    const int tid = threadIdx.x;
    const int ty  = tid >> 6;          // 0..3
    const int tx  = tid & 63;          // 0..63, active tx<56
    const int b       = blockIdx.x >> 3;
    const int cog     = blockIdx.x & 7;
    const int co_base = cog * CO_PB;

    const float* xb = x  + (size_t)b * CINN * NPX;
    const float* wb = Wt + (size_t)co_base * (CINN * 9);

    float v1[CO_PB]; int i1[CO_PB];
    #pragma unroll
    for (int co = 0; co < CO_PB; ++co) { v1[co] = -1.f; i1[co] = 0; }

    float* yo = y + (size_t)(b * COUTN + co_base) * NPX;

    #pragma unroll 1
    for (int g = 0; g < NSTRIP; ++g) {
        if (g) __syncthreads();        // WAR on xs

        // stage input rows 4g-1 .. 4g+4 (6 rows) x 58 cols x 32 ch, zero halo
        #pragma unroll 1
        for (int r = 0; r < 6; ++r) {
            int gr = 4 * g + r - 1;
            #pragma unroll 1
            for (int t = tid; t < 58 * CINN; t += THR) {
                int c   = t / 58;              // magic-mul
                int col = t - c * 58;
                int gc  = col - 1;
                float v = 0.f;
                if ((unsigned)gr < NSP && (unsigned)gc < NSP)
                    v = xb[(size_t)c * NPX + gr * NSP + gc];
                xs[r][col][c] = v;
            }
        }
        __syncthreads();

        float acc[CO_PB];
        #pragma unroll
        for (int co = 0; co < CO_PB; ++co) acc[co] = 0.f;

        if (tx < NSP) {
            // EXACT reference rounding order: kh outer, kw, c inner; single
            // f32 accumulator per (pixel,co); FMA per term (Eigen gebp/AVX2).
            #pragma unroll
            for (int kh = 0; kh < 3; ++kh) {
                #pragma unroll
                for (int kw = 0; kw < 3; ++kw) {
                    const float* wt = wb + kh * 3 + kw;   // + co*288 + c*9
                    #pragma unroll 4
                    for (int c = 0; c < CINN; ++c) {
                        float xv = xs[ty + kh][tx + kw][c];
                        #pragma unroll
                        for (int co = 0; co < CO_PB; ++co)
                            acc[co] = fmaf(xv, wt[co * (CINN * 9) + c * 9], acc[co]);
                    }
                }
            }
            int p = (4 * g + ty) * NSP + tx;
            #pragma unroll
            for (int co = 0; co < CO_PB; ++co) {
                float v = acc[co] + bias[co_base + co];   // separate f32 add
                v = fmaxf(v, 0.f);                        // relu
                yo[(size_t)co * NPX + p] = v;
                if (v > v1[co]) { v1[co] = v; i1[co] = p; }  // strict > = first idx
            }
        }
    }

    // block argmax per co: lexicographic (max val, min idx)
    const int wv = ty;                 // wave id 0..3
    #pragma unroll
    for (int co = 0; co < CO_PB; ++co) {
        float bv = v1[co]; int bi = i1[co];
        #pragma unroll
        for (int off = 32; off > 0; off >>= 1) {
            float ov = __shfl_xor(bv, off);
            int   oi = __shfl_xor(bi, off);
            if (ov > bv || (ov == bv && oi < bi)) { bv = ov; bi = oi; }
        }
        if ((tid & 63) == 0) { rv[wv][co] = bv; ri[wv][co] = bi; }
    }
    __syncthreads();
    if (tid < CO_PB) {
        float bv = rv[0][tid]; int bi = ri[0][tid];
        #pragma unroll
        for (int w = 1; w < 4; ++w) {
            float ov = rv[w][tid]; int oi = ri[w][tid];
            if (ov > bv || (ov == bv && oi < bi)) { bv = ov; bi = oi; }
        }
        amax[b * COUTN + co_base + tid] = bi;
    }
}

// ---- pass 2: in-place mask apply using the real templates input ----
__global__ __launch_bounds__(THR)
void mask_apply_pass2(float* __restrict__ y,
                      const float* __restrict__ tmpl,
                      const int* __restrict__ amax)
{
    const int bc = blockIdx.x;                    // (b*64+co)
    const int idx = amax[bc];
    const float* tp = tmpl + (size_t)idx * NPX;
    float* yp = y + (size_t)bc * NPX;
    #pragma unroll 1
    for (int p = threadIdx.x; p < NPX; p += THR) {
        float v = yp[p] * tp[p];                  // masked = y * masks
        yp[p] = v > 0.f ? v : 0.f;                // masked * (masked > 0)
    }
}

extern "C" void kernel_launch(void* const* d_in, const int* in_sizes, int n_in,
                              void* d_out, int out_size, void* d_ws, size_t ws_size,
                              hipStream_t stream)
{
    (void)in_sizes; (void)n_in; (void)ws_size; (void)out_size;
    const float* x  = (const float*)d_in[0];
    const float* W  = (const float*)d_in[1];
    const float* bi = (const float*)d_in[2];
    const float* tm = (const float*)d_in[3];
    float* out = (float*)d_out;
    int*   ws  = (int*)d_ws;       // 8192 ints

    dim3 grid1(NB * (COUTN / CO_PB));   // 1024 blocks
    hipLaunchKernelGGL(conv_emul_pass1, grid1, dim3(THR), 0, stream,
                       x, W, bi, out, ws);

    dim3 grid2(NB * COUTN);             // 8192 blocks
    hipLaunchKernelGGL(mask_apply_pass2, grid2, dim3(THR), 0, stream,
                       out, tm, ws);
}

// Round 5
// 403.795 us; speedup vs baseline: 1.9305x; 1.9305x over previous
//
#include <hip/hip_runtime.h>
#include <cstddef>

#define NSP   56
#define NPX   3136
#define CINN  32
#define COUTN 64
#define NB    128
#define CO_PB 8
#define NSTRIP 14            // 14 strips x 4 rows
#define THR   256            // 4 waves; ty=tid>>6 (0..3), tx=tid&63 (active<56)
#define XCOL  64             // padded row: col 0..2 junk, 3=left halo, 4..59=g0..55, 60=right halo

// ---- pass 0: transpose W [co][c][kh][kw] -> w2 [cog][kk][c][co8] ----
__global__ __launch_bounds__(THR)
void wtrans(const float* __restrict__ W, float* __restrict__ w2)
{
    int idx = blockIdx.x * THR + threadIdx.x;
    if (idx < COUTN * CINN * 9) {
        int co_l = idx & 7;
        int t    = idx >> 3;         // (cog*9 + kk)*32 + c
        int c    = t & 31;
        t >>= 5;                     // cog*9 + kk
        int kk   = t % 9;
        int cog  = t / 9;
        w2[idx] = W[(size_t)(cog * 8 + co_l) * (CINN * 9) + c * 9 + kk];
    }
}

// ---- pass 1: conv(+bias,relu) in XLA:CPU/Eigen rounding order, y + argmax ----
__global__ __launch_bounds__(THR, 3)
void conv_emul_pass1(const float* __restrict__ x,
                     const float* __restrict__ w2,   // [8][9][32][8]
                     const float* __restrict__ bias,
                     float* __restrict__ y,          // d_out: relu(conv+bias)
                     int* __restrict__ amax)         // [NB*COUTN] argmax idx
{
    __shared__ float xs[CINN][6][XCOL];   // 49152 B, row-contiguous per (c,r)
    __shared__ float rv[4][CO_PB];
    __shared__ int   ri[4][CO_PB];

    const int tid = threadIdx.x;
    const int ty  = tid >> 6;          // 0..3
    const int tx  = tid & 63;          // 0..63, active tx<56
    const int b       = blockIdx.x >> 3;
    const int cog     = blockIdx.x & 7;
    const int co_base = cog * CO_PB;

    const float* xb = x  + (size_t)b * CINN * NPX;
    const float* wq = w2 + (size_t)cog * (9 * CINN * CO_PB);  // uniform

    float v1[CO_PB]; int i1[CO_PB];
    #pragma unroll
    for (int co = 0; co < CO_PB; ++co) { v1[co] = -1.f; i1[co] = 0; }

    float* yo = y + (size_t)(b * COUTN + co_base) * NPX;

    #pragma unroll 1
    for (int g = 0; g < NSTRIP; ++g) {
        if (g) __syncthreads();        // WAR on xs

        // stage rows 4g-1..4g+4 (6) x 56 cols x 32 ch as float4; zero halo rows
        #pragma unroll 1
        for (int q = tid; q < CINN * 6 * 14; q += THR) {   // 2688 float4
            int c   = q / 84;
            int rem = q - c * 84;
            int r6  = rem / 14;
            int v4  = rem - r6 * 14;
            int gr  = 4 * g + r6 - 1;
            float4 val = make_float4(0.f, 0.f, 0.f, 0.f);
            if ((unsigned)gr < (unsigned)NSP)
                val = *(const float4*)(xb + (size_t)c * NPX + gr * NSP + 4 * v4);
            *(float4*)&xs[c][r6][4 + 4 * v4] = val;
        }
        if (tid < CINN * 6) {          // left/right halo cols
            int c = tid / 6, r6 = tid - 6 * (tid / 6);
            xs[c][r6][3]  = 0.f;
            xs[c][r6][60] = 0.f;
        }
        __syncthreads();

        float acc[CO_PB];
        #pragma unroll
        for (int co = 0; co < CO_PB; ++co) acc[co] = 0.f;

        if (tx < NSP) {
            // EXACT ref rounding order: kh -> kw -> c, single f32 acc, FMA per
            // term (zero-padding terms included via staged zeros: exact no-ops)
            #pragma unroll
            for (int kh = 0; kh < 3; ++kh) {
                #pragma unroll
                for (int kw = 0; kw < 3; ++kw) {
                    const float* wk = wq + (kh * 3 + kw) * (CINN * CO_PB); // uniform
                    #pragma unroll 4
                    for (int c = 0; c < CINN; ++c) {
                        float xv = xs[c][ty + kh][tx + kw + 3];
                        #pragma unroll
                        for (int co = 0; co < CO_PB; ++co)
                            acc[co] = fmaf(xv, wk[c * CO_PB + co], acc[co]);
                    }
                }
            }
            int p = (4 * g + ty) * NSP + tx;
            #pragma unroll
            for (int co = 0; co < CO_PB; ++co) {
                float v = acc[co] + bias[co_base + co];   // separate f32 add
                v = fmaxf(v, 0.f);
                yo[(size_t)co * NPX + p] = v;
                if (v > v1[co]) { v1[co] = v; i1[co] = p; }  // strict > = first idx
            }
        }
    }

    // block argmax per co: lexicographic (max val, min idx)
    #pragma unroll
    for (int co = 0; co < CO_PB; ++co) {
        float bv = v1[co]; int bi = i1[co];
        #pragma unroll
        for (int off = 32; off > 0; off >>= 1) {
            float ov = __shfl_xor(bv, off);
            int   oi = __shfl_xor(bi, off);
            if (ov > bv || (ov == bv && oi < bi)) { bv = ov; bi = oi; }
        }
        if ((tid & 63) == 0) { rv[ty][co] = bv; ri[ty][co] = bi; }
    }
    __syncthreads();
    if (tid < CO_PB) {
        float bv = rv[0][tid]; int bi = ri[0][tid];
        #pragma unroll
        for (int w = 1; w < 4; ++w) {
            float ov = rv[w][tid]; int oi = ri[w][tid];
            if (ov > bv || (ov == bv && oi < bi)) { bv = ov; bi = oi; }
        }
        amax[b * COUTN + co_base + tid] = bi;
    }
}

// ---- pass 2: in-place mask apply using the real templates input ----
__global__ __launch_bounds__(THR)
void mask_apply_pass2(float* __restrict__ y,
                      const float* __restrict__ tmpl,
                      const int* __restrict__ amax)
{
    const int bc = blockIdx.x;                    // (b*64+co)
    const int idx = amax[bc];
    const float* tp = tmpl + (size_t)idx * NPX;
    float* yp = y + (size_t)bc * NPX;
    #pragma unroll 1
    for (int p = threadIdx.x; p < NPX; p += THR) {
        float v = yp[p] * tp[p];                  // masked = y * masks
        yp[p] = v > 0.f ? v : 0.f;                // masked * (masked > 0)
    }
}

extern "C" void kernel_launch(void* const* d_in, const int* in_sizes, int n_in,
                              void* d_out, int out_size, void* d_ws, size_t ws_size,
                              hipStream_t stream)
{
    (void)in_sizes; (void)n_in; (void)ws_size; (void)out_size;
    const float* x  = (const float*)d_in[0];
    const float* W  = (const float*)d_in[1];
    const float* bi = (const float*)d_in[2];
    const float* tm = (const float*)d_in[3];
    float* out = (float*)d_out;
    int*   amax = (int*)d_ws;                           // 32 KB
    float* w2   = (float*)((char*)d_ws + 32768);        // 72 KB

    hipLaunchKernelGGL(wtrans, dim3(72), dim3(THR), 0, stream, W, w2);

    dim3 grid1(NB * (COUTN / CO_PB));   // 1024 blocks
    hipLaunchKernelGGL(conv_emul_pass1, grid1, dim3(THR), 0, stream,
                       x, w2, bi, out, amax);

    dim3 grid2(NB * COUTN);             // 8192 blocks
    hipLaunchKernelGGL(mask_apply_pass2, grid2, dim3(THR), 0, stream,
                       out, tm, amax);
}